// Round 13
// baseline (104.220 us; speedup 1.0000x reference)
//
#include <hip/hip_runtime.h>
#include <math.h>

// Problem constants (match reference)
#define Bdim 8
#define Lq   256
#define Hd   128

static constexpr float kNEG = -4294967295.0f;           // -(2^32)+1 as f32
static constexpr float kScale = 0.17677669529663687f;   // 1/sqrt(32)
static constexpr float kUni = 0.00390625f;              // 1/256 (exact)

typedef float f32x4 __attribute__((ext_vector_type(4)));

// ---------------------------------------------------------------------------
// Projections (fused abs_pos adds), W rows read DIRECTLY (contiguous 512B per
// output channel; 192 KB total -> L2-resident, 4x redundancy L1-served).
// 512 threads (8 waves/block): o = tid&127, rh = tid>>7, 2 rows/thread.
// ---------------------------------------------------------------------------
__global__ __launch_bounds__(512) void proj_kernel(
    const float* __restrict__ queries, const float* __restrict__ keys,
    const float* __restrict__ absK, const float* __restrict__ absV,
    const float* __restrict__ Wq, const float* __restrict__ Wk,
    const float* __restrict__ Wv,
    const float* __restrict__ bq, const float* __restrict__ bk,
    const float* __restrict__ bv,
    float* __restrict__ Qb, float* __restrict__ Kb, float* __restrict__ Vb)
{
    constexpr int R = 8;
    __shared__ float xq[R][Hd];
    __shared__ float xk[R][Hd];
    const int row0 = blockIdx.x * R;
    const int tid = threadIdx.x;
    #pragma unroll
    for (int k = 0; k < 2; ++k) {
        const int e = tid + k * 512;
        const int r = e >> 7, c = e & 127;
        xq[r][c] = queries[(row0 + r) * Hd + c];
        xk[r][c] = keys[(row0 + r) * Hd + c];
    }
    __syncthreads();

    const int o = tid & 127, rh = tid >> 7;
    const int r0 = rh * 2, r1 = rh * 2 + 1;
    const float* __restrict__ wqr = Wq + o * Hd;
    const float* __restrict__ wkr = Wk + o * Hd;
    const float* __restrict__ wvr = Wv + o * Hd;

    float qa0 = bq[o], qa1 = qa0;
    float ka0 = bk[o] + absK[(row0 + r0) * Hd + o];
    float ka1 = bk[o] + absK[(row0 + r1) * Hd + o];
    float va0 = bv[o] + absV[(row0 + r0) * Hd + o];
    float va1 = bv[o] + absV[(row0 + r1) * Hd + o];

    #pragma unroll 4
    for (int i4 = 0; i4 < 32; ++i4) {
        const f32x4 wq4 = *(const f32x4*)(wqr + i4 * 4);
        const f32x4 wk4 = *(const f32x4*)(wkr + i4 * 4);
        const f32x4 wv4 = *(const f32x4*)(wvr + i4 * 4);
        #pragma unroll
        for (int k = 0; k < 4; ++k) {
            const int i = i4 * 4 + k;
            const float x0 = xq[r0][i], x1 = xq[r1][i];
            const float y0 = xk[r0][i], y1 = xk[r1][i];
            qa0 += x0 * wq4[k]; qa1 += x1 * wq4[k];
            ka0 += y0 * wk4[k]; ka1 += y1 * wk4[k];
            va0 += y0 * wv4[k]; va1 += y1 * wv4[k];
        }
    }
    Qb[(row0 + r0) * Hd + o] = qa0;  Qb[(row0 + r1) * Hd + o] = qa1;
    Kb[(row0 + r0) * Hd + o] = ka0;  Kb[(row0 + r1) * Hd + o] = ka1;
    Vb[(row0 + r0) * Hd + o] = va0;  Vb[(row0 + r1) * Hd + o] = va1;
}

// ---------------------------------------------------------------------------
// Fused attention v10 = r8's balanced structure with 64B/lane streams and
// inlined mask handling. 1024 blocks = (b:8)x(hp:2)x(j:64); wave w -> head
// hp*2+(w&1), complementary pair p=j*2+(w>>1): l0=p, l1=255-p (constant 257
// rows/wave -> per-CU balance; bid&7=b pins batch->XCD for K/V L2 locality).
// Lane map: half=lane&1 (16-ch half of head), mo=lane>>1 (m row in 32-row
// tile); per-lane loads 4x f32x4 = 64B. Tiles: 8 x 32 rows; scores s[8]/l.
// Mask: wave-local u8-vs-i32 detection (8 dwords/lane scan + ballot); masked
// rows exact uniform 1/256. Zero LDS, zero barriers, 16 waves/CU.
// ---------------------------------------------------------------------------
__global__ __launch_bounds__(256, 4) void attn_kernel(
    const float* __restrict__ Qb, const float* __restrict__ Kb,
    const float* __restrict__ Vb,
    const float* __restrict__ tK, const float* __restrict__ tV,
    const unsigned char* __restrict__ mraw, float* __restrict__ out)
{
    const int bid = blockIdx.x;
    const int b  = bid & 7;
    const int hp = (bid >> 3) & 1;
    const int j  = bid >> 4;                // 0..63

    const int tid = threadIdx.x;
    const int w = tid >> 6;
    const int lane = tid & 63;
    const int h = hp * 2 + (w & 1);
    const int p = j * 2 + (w >> 1);         // 0..127
    const int l0 = p;
    const int l1 = 255 - p;
    const int half = lane & 1;
    const int mo = lane >> 1;               // 0..31: m row within tile
    const int ch = h * 32 + half * 16;

    // ---- wave-local mask-encoding detection (nonzero byte at i%4!=0?) ----
    bool is_u8;
    {
        const unsigned int* r32 = (const unsigned int*)mraw;
        unsigned int acc = 0;
        #pragma unroll
        for (int k = 0; k < 8; ++k) acc |= r32[lane + k * 64] & 0xFFFFFF00u;
        is_u8 = (__ballot(acc != 0) != 0);
    }
    const int mi0 = b * Lq + l0, mi1 = b * Lq + l1;
    const bool mk0 = is_u8 ? (mraw[mi0] != 0) : (((const int*)mraw)[mi0] != 0);
    const bool mk1 = is_u8 ? (mraw[mi1] != 0) : (((const int*)mraw)[mi1] != 0);

    // Q rows: 16 ch per lane, pre-scaled by 1/sqrt(D)
    const float* q0b = Qb + ((size_t)b * Lq + l0) * Hd + ch;
    const float* q1b = Qb + ((size_t)b * Lq + l1) * Hd + ch;
    f32x4 q0[4], q1[4];
    #pragma unroll
    for (int g = 0; g < 4; ++g) {
        q0[g] = *(const f32x4*)(q0b + g * 4) * kScale;
        q1[g] = *(const f32x4*)(q1b + g * 4) * kScale;
    }

    const int ntc0 = (l0 >> 5) + 1, ntc1 = (l1 >> 5) + 1;   // causal 32-tiles
    const int n10 = mk0 ? 0 : ntc0, n11 = mk1 ? 0 : ntc1;   // phase-1 bounds
    const int NT1 = (n10 > n11) ? n10 : n11;
    const int n20 = mk0 ? 8 : ntc0, n21 = mk1 ? 8 : ntc1;   // phase-2 bounds

    const float* kpt = Kb + (size_t)b * Lq * Hd + (size_t)mo * Hd + ch;
    const float* vpt = Vb + (size_t)b * Lq * Hd + (size_t)mo * Hd + ch;
    const float* t0p = tK + (((size_t)b * Lq + l0) * Lq + mo) * Hd + ch;
    const float* t1p = tK + (((size_t)b * Lq + l1) * Lq + mo) * Hd + ch;
    const float* u0p = tV + (((size_t)b * Lq + l0) * Lq + mo) * Hd + ch;
    const float* u1p = tV + (((size_t)b * Lq + l1) * Lq + mo) * Hd + ch;

    // ---- phase 1: scores in registers (K tile shared by both l's) ----
    float s0[8], s1[8];
    #pragma unroll
    for (int t = 0; t < 8; ++t) { s0[t] = kNEG; s1[t] = kNEG; }

    #pragma unroll
    for (int t = 0; t < 8; ++t) {
        if (t < NT1) {
            f32x4 kk[4];
            #pragma unroll
            for (int g = 0; g < 4; ++g)
                kk[g] = *(const f32x4*)(kpt + t * 4096 + g * 4);
            const int m = t * 32 + mo;
            if (t < n10) {
                float pp = 0.f;
                #pragma unroll
                for (int g = 0; g < 4; ++g) {
                    const f32x4 sa = kk[g] + *(const f32x4*)(t0p + t * 4096 + g * 4);
                    pp += q0[g].x * sa.x + q0[g].y * sa.y
                        + q0[g].z * sa.z + q0[g].w * sa.w;
                }
                pp += __shfl_xor(pp, 1);
                s0[t] = (m <= l0) ? pp : kNEG;
            }
            if (t < n11) {
                float pp = 0.f;
                #pragma unroll
                for (int g = 0; g < 4; ++g) {
                    const f32x4 sa = kk[g] + *(const f32x4*)(t1p + t * 4096 + g * 4);
                    pp += q1[g].x * sa.x + q1[g].y * sa.y
                        + q1[g].z * sa.z + q1[g].w * sa.w;
                }
                pp += __shfl_xor(pp, 1);
                s1[t] = (m <= l1) ? pp : kNEG;
            }
        }
    }

    // ---- softmax in registers (reduce over mo = lane bits 1..5) ----
    if (!mk0) {
        float mx = s0[0];
        #pragma unroll
        for (int t = 1; t < 8; ++t) mx = fmaxf(mx, s0[t]);
        #pragma unroll
        for (int d = 2; d < 64; d <<= 1) mx = fmaxf(mx, __shfl_xor(mx, d));
        float sum = 0.f;
        #pragma unroll
        for (int t = 0; t < 8; ++t) { s0[t] = expf(s0[t] - mx); sum += s0[t]; }
        #pragma unroll
        for (int d = 2; d < 64; d <<= 1) sum += __shfl_xor(sum, d);
        const float inv = 1.0f / sum;
        #pragma unroll
        for (int t = 0; t < 8; ++t) s0[t] *= inv;
    } else {
        #pragma unroll
        for (int t = 0; t < 8; ++t) s0[t] = kUni;
    }
    if (!mk1) {
        float mx = s1[0];
        #pragma unroll
        for (int t = 1; t < 8; ++t) mx = fmaxf(mx, s1[t]);
        #pragma unroll
        for (int d = 2; d < 64; d <<= 1) mx = fmaxf(mx, __shfl_xor(mx, d));
        float sum = 0.f;
        #pragma unroll
        for (int t = 0; t < 8; ++t) { s1[t] = expf(s1[t] - mx); sum += s1[t]; }
        #pragma unroll
        for (int d = 2; d < 64; d <<= 1) sum += __shfl_xor(sum, d);
        const float inv = 1.0f / sum;
        #pragma unroll
        for (int t = 0; t < 8; ++t) s1[t] *= inv;
    } else {
        #pragma unroll
        for (int t = 0; t < 8; ++t) s1[t] = kUni;
    }

    // ---- phase 2: output (V tile shared; weights lane-aligned with rows) --
    f32x4 a0[4] = {{0,0,0,0},{0,0,0,0},{0,0,0,0},{0,0,0,0}};
    f32x4 a1[4] = {{0,0,0,0},{0,0,0,0},{0,0,0,0},{0,0,0,0}};
    const int NT2 = (n20 > n21) ? n20 : n21;
    #pragma unroll
    for (int t = 0; t < 8; ++t) {
        if (t < NT2) {
            f32x4 vv[4];
            #pragma unroll
            for (int g = 0; g < 4; ++g)
                vv[g] = *(const f32x4*)(vpt + t * 4096 + g * 4);
            if (t < n20) {
                const float aw = s0[t];
                #pragma unroll
                for (int g = 0; g < 4; ++g)
                    a0[g] += aw * (vv[g] + *(const f32x4*)(u0p + t * 4096 + g * 4));
            }
            if (t < n21) {
                const float aw = s1[t];
                #pragma unroll
                for (int g = 0; g < 4; ++g)
                    a1[g] += aw * (vv[g] + *(const f32x4*)(u1p + t * 4096 + g * 4));
            }
        }
    }
    // reduce over the 32 mo lane-groups (lane bits 1..5)
    #pragma unroll
    for (int d = 2; d < 64; d <<= 1) {
        #pragma unroll
        for (int g = 0; g < 4; ++g) {
            a0[g].x += __shfl_xor(a0[g].x, d); a0[g].y += __shfl_xor(a0[g].y, d);
            a0[g].z += __shfl_xor(a0[g].z, d); a0[g].w += __shfl_xor(a0[g].w, d);
            a1[g].x += __shfl_xor(a1[g].x, d); a1[g].y += __shfl_xor(a1[g].y, d);
            a1[g].z += __shfl_xor(a1[g].z, d); a1[g].w += __shfl_xor(a1[g].w, d);
        }
    }
    if (mo == 0) {
        float* o0 = out + ((size_t)b * Lq + l0) * Hd + ch;
        float* o1 = out + ((size_t)b * Lq + l1) * Hd + ch;
        #pragma unroll
        for (int g = 0; g < 4; ++g) {
            *(f32x4*)(o0 + g * 4) = a0[g];
            *(f32x4*)(o1 + g * 4) = a1[g];
        }
    }
}

// ---------------------------------------------------------------------------
extern "C" void kernel_launch(void* const* d_in, const int* in_sizes, int n_in,
                              void* d_out, int out_size, void* d_ws, size_t ws_size,
                              hipStream_t stream) {
    const float* queries = (const float*)d_in[0];
    const float* keys    = (const float*)d_in[1];
    const float* tK      = (const float*)d_in[2];
    const float* tV      = (const float*)d_in[3];
    const float* absK    = (const float*)d_in[4];
    const float* absV    = (const float*)d_in[5];
    const float* Wq      = (const float*)d_in[6];
    const float* bq      = (const float*)d_in[7];
    const float* Wk      = (const float*)d_in[8];
    const float* bk      = (const float*)d_in[9];
    const float* Wv      = (const float*)d_in[10];
    const float* bv      = (const float*)d_in[11];
    const unsigned char* tmask_raw = (const unsigned char*)d_in[12];
    // d_in[13] (attn_mask) is deterministic triu(k=1) -> handled in-kernel.

    float* outp = (float*)d_out;

    const int rows = Bdim * Lq;                    // 2048
    float* Qb = (float*)d_ws;                      // 1 MB
    float* Kb = Qb + (size_t)rows * Hd;            // 1 MB
    float* Vb = Kb + (size_t)rows * Hd;            // 1 MB

    proj_kernel<<<rows / 8, 512, 0, stream>>>(queries, keys, absK, absV,
                                              Wq, Wk, Wv, bq, bk, bv,
                                              Qb, Kb, Vb);
    attn_kernel<<<1024, 256, 0, stream>>>(Qb, Kb, Vb, tK, tV, tmask_raw, outp);
}

// Round 14
// 81.075 us; speedup vs baseline: 1.2855x; 1.2855x over previous
//
#include <hip/hip_runtime.h>
#include <math.h>

// Problem constants (match reference)
#define Bdim 8
#define Lq   256
#define Hd   128

static constexpr float kNEG = -4294967295.0f;           // -(2^32)+1 as f32
static constexpr float kScale = 0.17677669529663687f;   // 1/sqrt(32)
static constexpr float kUni = 0.00390625f;              // 1/256 (exact)

typedef float f32x4 __attribute__((ext_vector_type(4)));

// ---------------------------------------------------------------------------
// prep: blocks 0-11 transpose Wq/Wk/Wv (64x64 LDS tiles, coalesced both ways);
//       block 12 normalizes the bool time_mask (u8 vs i32 auto-detect).
// ---------------------------------------------------------------------------
__global__ __launch_bounds__(256) void prep_kernel(
    const float* __restrict__ Wq, const float* __restrict__ Wk,
    const float* __restrict__ Wv, const unsigned char* __restrict__ raw,
    float* __restrict__ Wt, int* __restrict__ outmask)
{
    const int blk = blockIdx.x;
    if (blk < 12) {
        __shared__ float tile[64][65];
        const int mi = blk >> 2;
        const float* W = (mi == 0) ? Wq : (mi == 1) ? Wk : Wv;
        float* WT = Wt + mi * (Hd * Hd);
        const int ti = blk & 3;
        const int r0 = (ti >> 1) * 64, c0 = (ti & 1) * 64;
        #pragma unroll
        for (int k = 0; k < 16; ++k) {
            const int e = threadIdx.x + k * 256;
            const int r = e >> 6, c = e & 63;
            tile[r][c] = W[(r0 + r) * Hd + (c0 + c)];
        }
        __syncthreads();
        #pragma unroll
        for (int k = 0; k < 16; ++k) {
            const int e = threadIdx.x + k * 256;
            const int r = e >> 6, c = e & 63;
            WT[(c0 + r) * Hd + (r0 + c)] = tile[c][r];
        }
    } else {
        __shared__ int cnt;
        if (threadIdx.x == 0) cnt = 0;
        __syncthreads();
        const int n = Bdim * Lq;
        for (int i = threadIdx.x; i < n; i += 256)
            if ((i & 3) && raw[i]) atomicAdd(&cnt, 1);
        __syncthreads();
        const bool is_u8 = (cnt > 0);
        const int* raw32 = (const int*)raw;
        for (int i = threadIdx.x; i < n; i += 256) {
            const int v = is_u8 ? (int)raw[i] : raw32[i];
            outmask[i] = (v != 0) ? 1 : 0;
        }
    }
}

// ---------------------------------------------------------------------------
// Projections (fused abs_pos adds), W pre-transposed so loads are coalesced.
// 512 threads (8 waves/block): o = tid&127, rh = tid>>7, 2 rows/thread.
// ---------------------------------------------------------------------------
__global__ __launch_bounds__(512) void proj_kernel(
    const float* __restrict__ queries, const float* __restrict__ keys,
    const float* __restrict__ absK, const float* __restrict__ absV,
    const float* __restrict__ Wt,
    const float* __restrict__ bq, const float* __restrict__ bk,
    const float* __restrict__ bv,
    float* __restrict__ Qb, float* __restrict__ Kb, float* __restrict__ Vb)
{
    constexpr int R = 8;
    __shared__ float xq[R][Hd];
    __shared__ float xk[R][Hd];
    const int row0 = blockIdx.x * R;
    const int tid = threadIdx.x;
    #pragma unroll
    for (int k = 0; k < 2; ++k) {
        const int e = tid + k * 512;
        const int r = e >> 7, c = e & 127;
        xq[r][c] = queries[(row0 + r) * Hd + c];
        xk[r][c] = keys[(row0 + r) * Hd + c];
    }
    __syncthreads();

    const int o = tid & 127, rh = tid >> 7;
    const int r0 = rh * 2, r1 = rh * 2 + 1;
    const float* __restrict__ Wtq = Wt;
    const float* __restrict__ Wtk = Wt + Hd * Hd;
    const float* __restrict__ Wtv = Wt + 2 * Hd * Hd;

    float qa0 = bq[o], qa1 = qa0;
    float ka0 = bk[o] + absK[(row0 + r0) * Hd + o];
    float ka1 = bk[o] + absK[(row0 + r1) * Hd + o];
    float va0 = bv[o] + absV[(row0 + r0) * Hd + o];
    float va1 = bv[o] + absV[(row0 + r1) * Hd + o];

    #pragma unroll 4
    for (int i = 0; i < Hd; ++i) {
        const float wq = Wtq[i * Hd + o];
        const float wk = Wtk[i * Hd + o];
        const float wv = Wtv[i * Hd + o];
        const float x0 = xq[r0][i], x1 = xq[r1][i];
        const float y0 = xk[r0][i], y1 = xk[r1][i];
        qa0 += x0 * wq; qa1 += x1 * wq;
        ka0 += y0 * wk; ka1 += y1 * wk;
        va0 += y0 * wv; va1 += y1 * wv;
    }
    Qb[(row0 + r0) * Hd + o] = qa0;  Qb[(row0 + r1) * Hd + o] = qa1;
    Kb[(row0 + r0) * Hd + o] = ka0;  Kb[(row0 + r1) * Hd + o] = ka1;
    Vb[(row0 + r0) * Hd + o] = va0;  Vb[(row0 + r1) * Hd + o] = va1;
}

// ---------------------------------------------------------------------------
// Fused attention v11: 512 blocks = (b:8) x (h:4) x (pair-group:16).
// 512 threads = 8 waves; wave w -> complementary pair p = g*8+w: l0=p,
// l1=255-p (constant 257 rows/wave -> r8's proven balance). ONE head per
// block: K_h staged in LDS (256x32 f32, stride-36 pad -> 2-way aliasing =
// free), phase 1 from LDS; barrier; V_h re-staged over the SAME buffer;
// phase 2 from LDS. K/V HBM traffic: ~200 MB re-reads -> 32 MB read-once.
// Stream (tK/tV quarter-row) access, in-register softmax, masked-row
// uniform-1/256 path, and output writes identical to r8.
// Lane map: m_off=(lane>>2)&15, cg=lane&3, ch = h*32+cg*8.
// ---------------------------------------------------------------------------
__global__ __launch_bounds__(512, 4) void attn_kernel(
    const float* __restrict__ Qb, const float* __restrict__ Kb,
    const float* __restrict__ Vb,
    const float* __restrict__ tK, const float* __restrict__ tV,
    const int* __restrict__ tmask, float* __restrict__ out)
{
    const int bid = blockIdx.x;
    const int b = bid & 7;                  // batch -> XCD pin
    const int h = (bid >> 3) & 3;
    const int g = bid >> 5;                 // 0..15
    const int tid = threadIdx.x;
    const int w = tid >> 6;                 // 0..7
    const int lane = tid & 63;
    const int p = g * 8 + w;                // 0..127
    const int l0 = p, l1 = 255 - p;
    const int m_off = (lane >> 2) & 15;
    const int cg = lane & 3;
    const int ch = h * 32 + cg * 8;

    __shared__ float S[256 * 36];           // 36.9 KB: K_h, then V_h

    // ---- stage K_h (coalesced 128B quarters, once per block) ----
    {
        const int r = tid >> 1, half = tid & 1;
        const float* src = Kb + ((size_t)(b * Lq + r)) * Hd + h * 32 + half * 16;
        float* dst = &S[r * 36 + half * 16];
        #pragma unroll
        for (int qq = 0; qq < 4; ++qq)
            *(f32x4*)(dst + qq * 4) = *(const f32x4*)(src + qq * 4);
    }
    __syncthreads();

    // Q rows (pre-scaled by 1/sqrt(D))
    const float* q0b = Qb + ((size_t)b * Lq + l0) * Hd + ch;
    const float* q1b = Qb + ((size_t)b * Lq + l1) * Hd + ch;
    f32x4 q00 = *(const f32x4*)q0b * kScale, q01 = *(const f32x4*)(q0b + 4) * kScale;
    f32x4 q10 = *(const f32x4*)q1b * kScale, q11 = *(const f32x4*)(q1b + 4) * kScale;

    const bool mk0 = (tmask[b * Lq + l0] != 0);
    const bool mk1 = (tmask[b * Lq + l1] != 0);
    const int ntc0 = (l0 >> 4) + 1, ntc1 = (l1 >> 4) + 1;   // causal tiles
    const int n10 = mk0 ? 0 : ntc0, n11 = mk1 ? 0 : ntc1;   // phase-1 bounds
    const int NT1 = (n10 > n11) ? n10 : n11;
    const int n20 = mk0 ? 16 : ntc0, n21 = mk1 ? 16 : ntc1; // phase-2 bounds
    const int NT2 = (n20 > n21) ? n20 : n21;

    const float* t0p = tK + (((size_t)b * Lq + l0) * Lq + m_off) * Hd + ch;
    const float* t1p = tK + (((size_t)b * Lq + l1) * Lq + m_off) * Hd + ch;
    const float* u0p = tV + (((size_t)b * Lq + l0) * Lq + m_off) * Hd + ch;
    const float* u1p = tV + (((size_t)b * Lq + l1) * Lq + m_off) * Hd + ch;

    const float* kls = &S[m_off * 36 + cg * 8];   // row m_off, this lane's 8ch

    // ---- phase 1: scores in registers (K from LDS, shared by both l's) ----
    float s0[16], s1[16];
    #pragma unroll
    for (int t = 0; t < 16; ++t) { s0[t] = kNEG; s1[t] = kNEG; }

    #pragma unroll
    for (int t = 0; t < 16; ++t) {
        if (t < NT1) {
            const f32x4 ka = *(const f32x4*)(kls + t * 576);      // 576=16*36
            const f32x4 kb = *(const f32x4*)(kls + t * 576 + 4);
            const int m = t * 16 + m_off;
            if (t < n10) {
                const f32x4 sa = ka + *(const f32x4*)(t0p + t * 2048);
                const f32x4 sb = kb + *(const f32x4*)(t0p + t * 2048 + 4);
                float pp = q00.x*sa.x + q00.y*sa.y + q00.z*sa.z + q00.w*sa.w
                         + q01.x*sb.x + q01.y*sb.y + q01.z*sb.z + q01.w*sb.w;
                pp += __shfl_xor(pp, 1);
                pp += __shfl_xor(pp, 2);
                s0[t] = (m <= l0) ? pp : kNEG;
            }
            if (t < n11) {
                const f32x4 sa = ka + *(const f32x4*)(t1p + t * 2048);
                const f32x4 sb = kb + *(const f32x4*)(t1p + t * 2048 + 4);
                float pp = q10.x*sa.x + q10.y*sa.y + q10.z*sa.z + q10.w*sa.w
                         + q11.x*sb.x + q11.y*sb.y + q11.z*sb.z + q11.w*sb.w;
                pp += __shfl_xor(pp, 1);
                pp += __shfl_xor(pp, 2);
                s1[t] = (m <= l1) ? pp : kNEG;
            }
        }
    }

    // ---- softmax, fully in registers (reduce over m_off = lane bits 2..5) --
    if (!mk0) {
        float mx = s0[0];
        #pragma unroll
        for (int t = 1; t < 16; ++t) mx = fmaxf(mx, s0[t]);
        #pragma unroll
        for (int d = 4; d < 64; d <<= 1) mx = fmaxf(mx, __shfl_xor(mx, d));
        float sum = 0.f;
        #pragma unroll
        for (int t = 0; t < 16; ++t) { s0[t] = expf(s0[t] - mx); sum += s0[t]; }
        #pragma unroll
        for (int d = 4; d < 64; d <<= 1) sum += __shfl_xor(sum, d);
        const float inv = 1.0f / sum;
        #pragma unroll
        for (int t = 0; t < 16; ++t) s0[t] *= inv;
    } else {
        #pragma unroll
        for (int t = 0; t < 16; ++t) s0[t] = kUni;
    }
    if (!mk1) {
        float mx = s1[0];
        #pragma unroll
        for (int t = 1; t < 16; ++t) mx = fmaxf(mx, s1[t]);
        #pragma unroll
        for (int d = 4; d < 64; d <<= 1) mx = fmaxf(mx, __shfl_xor(mx, d));
        float sum = 0.f;
        #pragma unroll
        for (int t = 0; t < 16; ++t) { s1[t] = expf(s1[t] - mx); sum += s1[t]; }
        #pragma unroll
        for (int d = 4; d < 64; d <<= 1) sum += __shfl_xor(sum, d);
        const float inv = 1.0f / sum;
        #pragma unroll
        for (int t = 0; t < 16; ++t) s1[t] *= inv;
    } else {
        #pragma unroll
        for (int t = 0; t < 16; ++t) s1[t] = kUni;
    }

    __syncthreads();                        // all K reads done

    // ---- re-stage V_h over the same buffer ----
    {
        const int r = tid >> 1, half = tid & 1;
        const float* src = Vb + ((size_t)(b * Lq + r)) * Hd + h * 32 + half * 16;
        float* dst = &S[r * 36 + half * 16];
        #pragma unroll
        for (int qq = 0; qq < 4; ++qq)
            *(f32x4*)(dst + qq * 4) = *(const f32x4*)(src + qq * 4);
    }
    __syncthreads();

    // ---- phase 2: output (V from LDS; weights lane-aligned with rows) ----
    f32x4 a00 = {0,0,0,0}, a01 = {0,0,0,0};
    f32x4 a10 = {0,0,0,0}, a11 = {0,0,0,0};
    #pragma unroll
    for (int t = 0; t < 16; ++t) {
        if (t < NT2) {
            const f32x4 va = *(const f32x4*)(kls + t * 576);
            const f32x4 vb = *(const f32x4*)(kls + t * 576 + 4);
            if (t < n20) {
                const f32x4 ta = *(const f32x4*)(u0p + t * 2048);
                const f32x4 tb = *(const f32x4*)(u0p + t * 2048 + 4);
                const float aw = s0[t];
                a00 += aw * (va + ta);
                a01 += aw * (vb + tb);
            }
            if (t < n21) {
                const f32x4 ta = *(const f32x4*)(u1p + t * 2048);
                const f32x4 tb = *(const f32x4*)(u1p + t * 2048 + 4);
                const float aw = s1[t];
                a10 += aw * (va + ta);
                a11 += aw * (vb + tb);
            }
        }
    }
    // reduce over the 16 m_off lane-groups
    #pragma unroll
    for (int d = 4; d < 64; d <<= 1) {
        a00.x += __shfl_xor(a00.x, d); a00.y += __shfl_xor(a00.y, d);
        a00.z += __shfl_xor(a00.z, d); a00.w += __shfl_xor(a00.w, d);
        a01.x += __shfl_xor(a01.x, d); a01.y += __shfl_xor(a01.y, d);
        a01.z += __shfl_xor(a01.z, d); a01.w += __shfl_xor(a01.w, d);
        a10.x += __shfl_xor(a10.x, d); a10.y += __shfl_xor(a10.y, d);
        a10.z += __shfl_xor(a10.z, d); a10.w += __shfl_xor(a10.w, d);
        a11.x += __shfl_xor(a11.x, d); a11.y += __shfl_xor(a11.y, d);
        a11.z += __shfl_xor(a11.z, d); a11.w += __shfl_xor(a11.w, d);
    }
    if (m_off == 0) {
        float* o0 = out + ((size_t)b * Lq + l0) * Hd + ch;
        *(f32x4*)o0 = a00; *(f32x4*)(o0 + 4) = a01;
        float* o1 = out + ((size_t)b * Lq + l1) * Hd + ch;
        *(f32x4*)o1 = a10; *(f32x4*)(o1 + 4) = a11;
    }
}

// ---------------------------------------------------------------------------
extern "C" void kernel_launch(void* const* d_in, const int* in_sizes, int n_in,
                              void* d_out, int out_size, void* d_ws, size_t ws_size,
                              hipStream_t stream) {
    const float* queries = (const float*)d_in[0];
    const float* keys    = (const float*)d_in[1];
    const float* tK      = (const float*)d_in[2];
    const float* tV      = (const float*)d_in[3];
    const float* absK    = (const float*)d_in[4];
    const float* absV    = (const float*)d_in[5];
    const float* Wq      = (const float*)d_in[6];
    const float* bq      = (const float*)d_in[7];
    const float* Wk      = (const float*)d_in[8];
    const float* bk      = (const float*)d_in[9];
    const float* Wv      = (const float*)d_in[10];
    const float* bv      = (const float*)d_in[11];
    const unsigned char* tmask_raw = (const unsigned char*)d_in[12];
    // d_in[13] (attn_mask) is deterministic triu(k=1) -> handled in-kernel.

    float* outp = (float*)d_out;

    const int rows = Bdim * Lq;                    // 2048
    float* Qb = (float*)d_ws;                      // 1 MB
    float* Kb = Qb + (size_t)rows * Hd;            // 1 MB
    float* Vb = Kb + (size_t)rows * Hd;            // 1 MB
    int* tmask = (int*)(Vb + (size_t)rows * Hd);   // 8 KB
    float* Wt = (float*)(tmask + rows);            // 192 KB (3 transposed W)

    prep_kernel<<<13, 256, 0, stream>>>(Wq, Wk, Wv, tmask_raw, Wt, tmask);
    proj_kernel<<<rows / 8, 512, 0, stream>>>(queries, keys, absK, absV, Wt,
                                              bq, bk, bv, Qb, Kb, Vb);
    attn_kernel<<<512, 512, 0, stream>>>(Qb, Kb, Vb, tK, tV, tmask, outp);
}